// Round 4
// baseline (402.374 us; speedup 1.0000x reference)
//
#include <hip/hip_runtime.h>
#include <math.h>

// ---------------------------------------------------------------------------
// Mamba forward.
//   casts: hidden->hbf, in_proj_w->wbf, x_proj_w->xpwbf(128-row pad),
//          out_proj_w->owbf   (all bf16)
//   K1 gemm_bf16<1>: xz = hbf @ wbf^T -> xcpre fp32 (b,l,ch), zbf bf16
//   K2 conv_silu: causal conv4 + bias + SiLU -> xtbf (b,l,ch) bf16
//   K3 gemm_xproj (split-K=16 MFMA) + reduce_xdbl -> xdbl fp32 (b,l,96)
//   K4 gemm_nt<2>: delta = softplus(x_dbl[:,:64] @ dt_proj_w^T + dt_b) fp32
//   K5-7 chunked scan; round-4: one thread = one (b,d,chunk) x 16 states,
//        B/C staged in LDS (wave-uniform broadcast reads), no shuffles.
//   K8 gemm_bf16<0>: out = ybf @ owbf^T -> fp32 out
// ---------------------------------------------------------------------------

#define DMODEL 1024
#define DINNER 2048
#define DSTATE 16
#define DTRANK 64
#define BSZ    2
#define LSEQ   2048
#define NCHUNK 32
#define CLEN   64
#define SPLITK 16
#define KCH    (DINNER / SPLITK)   // 128
#define XDBL_N 96
#define XDBL_SZ (BSZ*LSEQ*XDBL_N)  // 393216
#define NROW16 (BSZ*DINNER*DSTATE) // 65536 state rows

typedef __attribute__((ext_vector_type(8))) short bf16x8;
typedef __attribute__((ext_vector_type(8))) unsigned short u16x8;
typedef __attribute__((ext_vector_type(4))) unsigned short u16x4;
typedef __attribute__((ext_vector_type(4))) float f32x4;

__device__ __forceinline__ float silu_f(float v) {
    return v / (1.f + __expf(-v));
}
__device__ __forceinline__ float softplus_f(float v) {
    return (v > 20.f) ? v : log1pf(expf(v));
}
__device__ __forceinline__ unsigned short f2bf(float f) {
    unsigned int u = __float_as_uint(f);
    unsigned int r = (u + 0x7fffu + ((u >> 16) & 1u)) >> 16;   // RNE
    return (unsigned short)r;
}
__device__ __forceinline__ float bf2f(unsigned short u) {
    return __uint_as_float(((unsigned int)u) << 16);
}
__device__ __forceinline__ void gl_lds16(const void* g, void* l) {
    __builtin_amdgcn_global_load_lds(
        (const __attribute__((address_space(1))) unsigned int*)g,
        (__attribute__((address_space(3))) unsigned int*)l, 16, 0, 0);
}

// ---------------------------------------------------------------------------
__global__ __launch_bounds__(256) void cast_bf16(
    const float* __restrict__ src, unsigned short* __restrict__ dst)
{
    size_t i = (size_t)blockIdx.x * 256 + threadIdx.x;
    float4 a = ((const float4*)src)[2 * i];
    float4 b = ((const float4*)src)[2 * i + 1];
    u16x8 v;
    v[0] = f2bf(a.x); v[1] = f2bf(a.y); v[2] = f2bf(a.z); v[3] = f2bf(a.w);
    v[4] = f2bf(b.x); v[5] = f2bf(b.y); v[6] = f2bf(b.z); v[7] = f2bf(b.w);
    *(u16x8*)(dst + 8 * i) = v;
}

// x_proj_w (96 x 2048) -> bf16 padded to 128 rows (rows 96..127 zero)
__global__ __launch_bounds__(256) void cast_xpw(
    const float* __restrict__ src, unsigned short* __restrict__ dst)
{
    int i = blockIdx.x * 256 + threadIdx.x;
    size_t o = (size_t)i * 8;
    int row = (int)(o >> 11);
    u16x8 v = {0, 0, 0, 0, 0, 0, 0, 0};
    if (row < 96) {
        float4 a = ((const float4*)src)[2 * i];
        float4 b = ((const float4*)src)[2 * i + 1];
        v[0] = f2bf(a.x); v[1] = f2bf(a.y); v[2] = f2bf(a.z); v[3] = f2bf(a.w);
        v[4] = f2bf(b.x); v[5] = f2bf(b.y); v[6] = f2bf(b.z); v[7] = f2bf(b.w);
    }
    *(u16x8*)(dst + o) = v;
}

// ---------------------------------------------------------------------------
// bf16 MFMA GEMM (NT): C[m,n] = sum_k A[m,k]*B[n,k]
// 128x128 tile, BK=32, 256 thr (4 waves), global_load_lds width-16 staging.
// EPI 0: C[m*ldc+n] fp32
// EPI 1: n<DINNER -> C[m*DINNER+n] fp32 ; else zb[m*DINNER+n-DINNER] bf16
// ---------------------------------------------------------------------------
template<int EPI>
__global__ __launch_bounds__(256) void gemm_bf16(
    const short* __restrict__ A, const short* __restrict__ B,
    float* __restrict__ C, int ldc, unsigned short* __restrict__ zb, int K)
{
    __shared__ __align__(16) short As[128 * 32];
    __shared__ __align__(16) short Bs[128 * 32];
    const int t = threadIdx.x;
    const int wave = t >> 6, lane = t & 63;
    const int m0 = blockIdx.y * 128, n0 = blockIdx.x * 128;
    const int wm = (wave & 1) * 64, wn = (wave >> 1) * 64;
    const int srow = t >> 2;
    const int sq = (t & 3) * 16;

    const short* Ag = A + (size_t)(m0 + srow) * K;
    const short* Bg = B + (size_t)(n0 + srow) * K;
    char* AsL0 = (char*)As + wave * 1024;
    char* AsL1 = (char*)As + 4096 + wave * 1024;
    char* BsL0 = (char*)Bs + wave * 1024;
    char* BsL1 = (char*)Bs + 4096 + wave * 1024;

    const int quad = lane >> 4, l16 = lane & 15;
    const int aoff = (wm + l16) * 32 + quad * 8;
    const int boff = (wn + l16) * 32 + quad * 8;

    f32x4 acc[4][4];
#pragma unroll
    for (int i = 0; i < 4; i++)
#pragma unroll
        for (int j = 0; j < 4; j++) {
            f32x4 z = {0.f, 0.f, 0.f, 0.f};
            acc[i][j] = z;
        }

    for (int k0 = 0; k0 < K; k0 += 32) {
        __syncthreads();
        gl_lds16((const char*)(Ag + k0) + sq, AsL0);
        gl_lds16((const char*)(Ag + (size_t)64 * K + k0) + sq, AsL1);
        gl_lds16((const char*)(Bg + k0) + sq, BsL0);
        gl_lds16((const char*)(Bg + (size_t)64 * K + k0) + sq, BsL1);
        __syncthreads();
        bf16x8 af[4], bfr[4];
#pragma unroll
        for (int i = 0; i < 4; i++) {
            af[i]  = *(const bf16x8*)(As + aoff + i * 16 * 32);
            bfr[i] = *(const bf16x8*)(Bs + boff + i * 16 * 32);
        }
#pragma unroll
        for (int i = 0; i < 4; i++)
#pragma unroll
            for (int j = 0; j < 4; j++)
                acc[i][j] = __builtin_amdgcn_mfma_f32_16x16x32_bf16(
                    af[i], bfr[j], acc[i][j], 0, 0, 0);
    }

    // C/D layout: col(n) = lane&15, row(m) = quad*4 + reg
#pragma unroll
    for (int i = 0; i < 4; i++) {
        int mrow = m0 + wm + i * 16 + quad * 4;
#pragma unroll
        for (int j = 0; j < 4; j++) {
            int n = n0 + wn + j * 16 + l16;
            if (EPI == 1 && n0 >= DINNER) {
#pragma unroll
                for (int r = 0; r < 4; r++)
                    zb[(size_t)(mrow + r) * DINNER + (n - DINNER)] =
                        f2bf(acc[i][j][r]);
            } else {
                int ld = (EPI == 1) ? DINNER : ldc;
#pragma unroll
                for (int r = 0; r < 4; r++)
                    C[(size_t)(mrow + r) * ld + n] = acc[i][j][r];
            }
        }
    }
}

// ---------------------------------------------------------------------------
// K3: x_dbl split-K MFMA. grid (32, SPLITK). Partials -> ppart[kc][4096][96].
// ---------------------------------------------------------------------------
__global__ __launch_bounds__(256) void gemm_xproj(
    const short* __restrict__ Abf, const short* __restrict__ Bbf,
    float* __restrict__ ppart)
{
    __shared__ __align__(16) short As[128 * 32];
    __shared__ __align__(16) short Bs[128 * 32];
    const int t = threadIdx.x;
    const int wave = t >> 6, lane = t & 63;
    const int m0 = blockIdx.x * 128;
    const int kc = blockIdx.y;
    const int srow = t >> 2;
    const int sq = (t & 3) * 16;

    const short* Ag = Abf + (size_t)(m0 + srow) * DINNER;
    const short* Bg = Bbf + (size_t)srow * DINNER;
    char* AsL0 = (char*)As + wave * 1024;
    char* AsL1 = (char*)As + 4096 + wave * 1024;
    char* BsL0 = (char*)Bs + wave * 1024;
    char* BsL1 = (char*)Bs + 4096 + wave * 1024;

    const int quad = lane >> 4, l16 = lane & 15;
    const int wm = wave * 32;

    f32x4 acc[2][6];
#pragma unroll
    for (int i = 0; i < 2; i++)
#pragma unroll
        for (int j = 0; j < 6; j++) {
            f32x4 z = {0.f, 0.f, 0.f, 0.f};
            acc[i][j] = z;
        }

    for (int k0 = kc * KCH; k0 < kc * KCH + KCH; k0 += 32) {
        __syncthreads();
        gl_lds16((const char*)(Ag + k0) + sq, AsL0);
        gl_lds16((const char*)(Ag + (size_t)64 * DINNER + k0) + sq, AsL1);
        gl_lds16((const char*)(Bg + k0) + sq, BsL0);
        gl_lds16((const char*)(Bg + (size_t)64 * DINNER + k0) + sq, BsL1);
        __syncthreads();
        bf16x8 af[2], bfr[6];
#pragma unroll
        for (int i = 0; i < 2; i++)
            af[i] = *(const bf16x8*)(As + (wm + i * 16 + l16) * 32 + quad * 8);
#pragma unroll
        for (int j = 0; j < 6; j++)
            bfr[j] = *(const bf16x8*)(Bs + (j * 16 + l16) * 32 + quad * 8);
#pragma unroll
        for (int i = 0; i < 2; i++)
#pragma unroll
            for (int j = 0; j < 6; j++)
                acc[i][j] = __builtin_amdgcn_mfma_f32_16x16x32_bf16(
                    af[i], bfr[j], acc[i][j], 0, 0, 0);
    }

    float* dst = ppart + (size_t)kc * XDBL_SZ;
#pragma unroll
    for (int i = 0; i < 2; i++) {
        int mrow = m0 + wm + i * 16 + quad * 4;
#pragma unroll
        for (int j = 0; j < 6; j++) {
            int n = j * 16 + l16;
#pragma unroll
            for (int r = 0; r < 4; r++)
                dst[(size_t)(mrow + r) * XDBL_N + n] = acc[i][j][r];
        }
    }
}

__global__ __launch_bounds__(256) void reduce_xdbl(
    const float* __restrict__ ppart, float* __restrict__ xdbl)
{
    int i = blockIdx.x * 256 + threadIdx.x;
    float s = 0.f;
#pragma unroll
    for (int c = 0; c < SPLITK; c++) s += ppart[(size_t)c * XDBL_SZ + i];
    xdbl[i] = s;
}

// ---------------------------------------------------------------------------
// fp32 NT GEMM (K4 only). EPI 2: softplus(acc + bias[n])
// ---------------------------------------------------------------------------
template<int EPI>
__global__ __launch_bounds__(256) void gemm_nt(
    const float* __restrict__ A, int lda,
    const float* __restrict__ B, int ldb,
    float* __restrict__ C, int ldc,
    const float* __restrict__ bias,
    int N, int K)
{
    __shared__ float As[16][68];
    __shared__ float Bs[16][68];
    const int m0 = blockIdx.y * 64;
    const int n0 = blockIdx.x * 64;
    const int t  = threadIdx.x;
    const int tx = t & 15, ty = t >> 4;
    const int lrow = t >> 2, kq = (t & 3) * 4;

    const float* Aptr = A + (size_t)(m0 + lrow) * lda + kq;
    const float* Bptr = B + (size_t)(n0 + lrow) * ldb + kq;
    const bool bok = (n0 + lrow) < N;

    float acc[4][4];
#pragma unroll
    for (int i = 0; i < 4; i++)
#pragma unroll
        for (int j = 0; j < 4; j++) acc[i][j] = 0.f;

    for (int k0 = 0; k0 < K; k0 += 16) {
        float4 av = *(const float4*)(Aptr + k0);
        float4 bv = make_float4(0.f, 0.f, 0.f, 0.f);
        if (bok) bv = *(const float4*)(Bptr + k0);
        __syncthreads();
        As[kq + 0][lrow] = av.x; As[kq + 1][lrow] = av.y;
        As[kq + 2][lrow] = av.z; As[kq + 3][lrow] = av.w;
        Bs[kq + 0][lrow] = bv.x; Bs[kq + 1][lrow] = bv.y;
        Bs[kq + 2][lrow] = bv.z; Bs[kq + 3][lrow] = bv.w;
        __syncthreads();
#pragma unroll
        for (int kk = 0; kk < 16; ++kk) {
            float4 a4 = *(const float4*)&As[kk][ty * 4];
            float4 b4 = *(const float4*)&Bs[kk][tx * 4];
            float ar[4] = {a4.x, a4.y, a4.z, a4.w};
            float br[4] = {b4.x, b4.y, b4.z, b4.w};
#pragma unroll
            for (int i = 0; i < 4; i++)
#pragma unroll
                for (int j = 0; j < 4; j++)
                    acc[i][j] = fmaf(ar[i], br[j], acc[i][j]);
        }
    }

    int n = n0 + tx * 4;
    if (n < N) {
#pragma unroll
        for (int i = 0; i < 4; i++) {
            int m = m0 + ty * 4 + i;
            float4 v = make_float4(acc[i][0], acc[i][1], acc[i][2], acc[i][3]);
            if (EPI == 2) {
                v.x = softplus_f(v.x + bias[n + 0]);
                v.y = softplus_f(v.y + bias[n + 1]);
                v.z = softplus_f(v.z + bias[n + 2]);
                v.w = softplus_f(v.w + bias[n + 3]);
            }
            *(float4*)(C + (size_t)m * ldc + n) = v;
        }
    }
}

// ---------------------------------------------------------------------------
// Causal conv4 + bias + SiLU, (b,l,ch) fp32 in, bf16 out. 4 ch per thread.
// ---------------------------------------------------------------------------
__global__ __launch_bounds__(256) void conv_silu(
    const float* __restrict__ xc, const float* __restrict__ convw,
    const float* __restrict__ convb, unsigned short* __restrict__ xtbf)
{
    int i = blockIdx.x * 256 + threadIdx.x;
    int c4 = i & 511;
    int m  = i >> 9;
    int l  = m & (LSEQ - 1);
    int ch = c4 * 4;
    const float4* base = (const float4*)xc + (size_t)m * 512 + c4;
    float4 zf = make_float4(0.f, 0.f, 0.f, 0.f);
    float4 x3 = base[0];
    float4 x2 = (l >= 1) ? base[-512]  : zf;
    float4 x1 = (l >= 2) ? base[-1024] : zf;
    float4 x0 = (l >= 3) ? base[-1536] : zf;
    float4 t0 = ((const float4*)convw)[ch + 0];
    float4 t1 = ((const float4*)convw)[ch + 1];
    float4 t2 = ((const float4*)convw)[ch + 2];
    float4 t3 = ((const float4*)convw)[ch + 3];
    float4 bv = ((const float4*)convb)[c4];
    u16x4 o;
    o[0] = f2bf(silu_f(bv.x + t0.x * x0.x + t0.y * x1.x + t0.z * x2.x + t0.w * x3.x));
    o[1] = f2bf(silu_f(bv.y + t1.x * x0.y + t1.y * x1.y + t1.z * x2.y + t1.w * x3.y));
    o[2] = f2bf(silu_f(bv.z + t2.x * x0.z + t2.y * x1.z + t2.z * x2.z + t2.w * x3.z));
    o[3] = f2bf(silu_f(bv.w + t3.x * x0.w + t3.y * x1.w + t3.z * x2.w + t3.w * x3.w));
    *(u16x4*)(xtbf + (size_t)m * DINNER + ch) = o;
}

// ---------------------------------------------------------------------------
// Chunked selective scan, round-4 structure:
// thread = one (b, d, chunk), all 16 states in registers.
// grid (DINNER/256, NCHUNK, BSZ); B (and C in phaseC) staged in LDS,
// per-step LDS reads are wave-uniform (free broadcast).
// P/S/H layout: [c][(b*DINNER+d)*16 + j], c-stride = 65536 floats.
// ---------------------------------------------------------------------------
__global__ __launch_bounds__(256) void scan_phaseA(
    const float* __restrict__ xdbl, const float* __restrict__ dlt,
    const unsigned short* __restrict__ xtbf, const float* __restrict__ A_log,
    float* __restrict__ Pbuf, float* __restrict__ Sbuf)
{
    __shared__ float Bsh[CLEN][16];
    const int d = blockIdx.x * 256 + threadIdx.x;
    const int c = blockIdx.y, b = blockIdx.z;
    // stage B rows: 64 l x 16 floats; thread (lr, p) loads one float4
    {
        int lr = threadIdx.x >> 2, p = threadIdx.x & 3;
        const float* src = xdbl +
            ((size_t)b * LSEQ + (size_t)c * CLEN + lr) * XDBL_N + DTRANK + p * 4;
        *(float4*)&Bsh[lr][p * 4] = *(const float4*)src;
    }
    __syncthreads();

    float A[16], P[16], S[16];
#pragma unroll
    for (int j = 0; j < 16; j++) {
        A[j] = -expf(A_log[d * DSTATE + j]);
        P[j] = 1.f; S[j] = 0.f;
    }
    size_t off = ((size_t)b * LSEQ + (size_t)c * CLEN) * DINNER + d;
    for (int ll = 0; ll < CLEN; ++ll, off += DINNER) {
        float dv = dlt[off];
        float xv = bf2f(xtbf[off]);
        float dx = dv * xv;
        f32x4 Bq[4];
#pragma unroll
        for (int q = 0; q < 4; q++) Bq[q] = *(const f32x4*)&Bsh[ll][q * 4];
#pragma unroll
        for (int j = 0; j < 16; j++) {
            float dA = __expf(dv * A[j]);
            P[j] *= dA;
            S[j] = fmaf(dA, S[j], dx * Bq[j >> 2][j & 3]);
        }
    }
    size_t o = ((size_t)c * BSZ * DINNER + (size_t)b * DINNER + d) * 16;
#pragma unroll
    for (int q = 0; q < 4; q++) {
        *(float4*)(Pbuf + o + q * 4) =
            make_float4(P[4 * q], P[4 * q + 1], P[4 * q + 2], P[4 * q + 3]);
        *(float4*)(Sbuf + o + q * 4) =
            make_float4(S[4 * q], S[4 * q + 1], S[4 * q + 2], S[4 * q + 3]);
    }
}

__global__ __launch_bounds__(256) void scan_phaseB(
    const float* __restrict__ Pbuf, const float* __restrict__ Sbuf,
    float* __restrict__ Hbuf)
{
    int r = blockIdx.x * 256 + threadIdx.x;   // 65536 state rows
    float run = 0.f;
    for (int c = 0; c < NCHUNK; ++c) {
        size_t o = (size_t)c * NROW16 + r;
        Hbuf[o] = run;
        run = Pbuf[o] * run + Sbuf[o];
    }
}

__global__ __launch_bounds__(256) void scan_phaseC(
    const float* __restrict__ xdbl, const float* __restrict__ dlt,
    const unsigned short* __restrict__ xtbf, const unsigned short* __restrict__ zbf,
    const float* __restrict__ A_log, const float* __restrict__ Dvec,
    const float* __restrict__ Hbuf, unsigned short* __restrict__ ybf)
{
    __shared__ float BCsh[CLEN][32];   // [l][0:16]=B, [l][16:32]=C
    const int d = blockIdx.x * 256 + threadIdx.x;
    const int c = blockIdx.y, b = blockIdx.z;
    {
        int lr = threadIdx.x >> 2, p = threadIdx.x & 3;
        const float* src = xdbl +
            ((size_t)b * LSEQ + (size_t)c * CLEN + lr) * XDBL_N + DTRANK;
        *(float4*)&BCsh[lr][p * 4]      = *(const float4*)(src + p * 4);
        *(float4*)&BCsh[lr][16 + p * 4] = *(const float4*)(src + 16 + p * 4);
    }
    __syncthreads();

    float A[16], h[16];
#pragma unroll
    for (int j = 0; j < 16; j++)
        A[j] = -expf(A_log[d * DSTATE + j]);
    size_t o = ((size_t)c * BSZ * DINNER + (size_t)b * DINNER + d) * 16;
#pragma unroll
    for (int q = 0; q < 4; q++) {
        float4 h4 = *(const float4*)(Hbuf + o + q * 4);
        h[4 * q] = h4.x; h[4 * q + 1] = h4.y; h[4 * q + 2] = h4.z; h[4 * q + 3] = h4.w;
    }
    float Dd = Dvec[d];
    size_t off = ((size_t)b * LSEQ + (size_t)c * CLEN) * DINNER + d;
    for (int ll = 0; ll < CLEN; ++ll, off += DINNER) {
        float dv = dlt[off];
        float xv = bf2f(xtbf[off]);
        float zv = bf2f(zbf[off]);
        float dx = dv * xv;
        f32x4 Bq[4], Cq[4];
#pragma unroll
        for (int q = 0; q < 4; q++) {
            Bq[q] = *(const f32x4*)&BCsh[ll][q * 4];
            Cq[q] = *(const f32x4*)&BCsh[ll][16 + q * 4];
        }
        float yp = 0.f;
#pragma unroll
        for (int j = 0; j < 16; j++) {
            float dA = __expf(dv * A[j]);
            h[j] = fmaf(dA, h[j], dx * Bq[j >> 2][j & 3]);
            yp = fmaf(h[j], Cq[j >> 2][j & 3], yp);
        }
        float yv = yp + Dd * xv;
        yv *= zv / (1.f + __expf(-zv));
        ybf[off] = f2bf(yv);
    }
}

// ---------------------------------------------------------------------------
extern "C" void kernel_launch(void* const* d_in, const int* in_sizes, int n_in,
                              void* d_out, int out_size, void* d_ws, size_t ws_size,
                              hipStream_t stream)
{
    const float* hidden     = (const float*)d_in[0];
    const float* in_proj_w  = (const float*)d_in[1];
    const float* conv_w     = (const float*)d_in[2];
    const float* conv_b     = (const float*)d_in[3];
    const float* x_proj_w   = (const float*)d_in[4];
    const float* dt_proj_w  = (const float*)d_in[5];
    const float* dt_proj_b  = (const float*)d_in[6];
    const float* A_log      = (const float*)d_in[7];
    const float* Dvec       = (const float*)d_in[8];
    const float* out_proj_w = (const float*)d_in[9];
    float* out = (float*)d_out;

    // workspace (float units), 28 MF = 112 MB:
    //  [0,8)     xcpre (K1->K2) / dlt (K4->scan)        [disjoint lifetimes]
    //  [8,12)    zbf   (bf16, 8M shorts)
    //  [12,16)   xtbf  (bf16, 8M shorts)
    //  [16,22)   ppart (K3->reduce) / Pbuf[16,18) Sbuf[18,20) Hbuf[20,22)
    //  [22,22.125)  xpwbf (bf16)
    //  [22.25,22.625) xdbl
    //  [23,24)   owbf (bf16)
    //  [24,26)   hbf (bf16) ; [26,28) wbf (bf16) ; ybf aliases [24,28)
    const size_t MF = 1024 * 1024;
    float* ws = (float*)d_ws;
    float* xcpre = ws;
    float* dlt   = ws;
    unsigned short* zbf  = (unsigned short*)(ws + 8 * MF);
    unsigned short* xtbf = (unsigned short*)(ws + 12 * MF);
    float* ppart = ws + 16 * MF;
    float* Pbuf  = ws + 16 * MF;
    float* Sbuf  = ws + 18 * MF;
    float* Hbuf  = ws + 20 * MF;
    unsigned short* xpwbf = (unsigned short*)(ws + 22 * MF);
    float* xdbl  = ws + 22 * MF + MF / 4;
    unsigned short* owbf = (unsigned short*)(ws + 23 * MF);
    unsigned short* hbf  = (unsigned short*)(ws + 24 * MF);
    unsigned short* wbf  = (unsigned short*)(ws + 26 * MF);
    unsigned short* ybf  = hbf;   // reused after K1

    const int M = BSZ * LSEQ;   // 4096

    // casts
    cast_bf16<<<2048, 256, 0, stream>>>(hidden, hbf);
    cast_bf16<<<2048, 256, 0, stream>>>(in_proj_w, wbf);
    cast_xpw<<<128, 256, 0, stream>>>(x_proj_w, xpwbf);

    // K1: xz = hidden @ in_proj_w^T (bf16 MFMA), x fp32 / z bf16
    gemm_bf16<1><<<dim3(2 * DINNER / 128, M / 128), 256, 0, stream>>>(
        (const short*)hbf, (const short*)wbf, xcpre, 0, zbf, DMODEL);

    // K2: conv + SiLU -> bf16 xt
    conv_silu<<<(M * 512) / 256, 256, 0, stream>>>(xcpre, conv_w, conv_b, xtbf);

    // cast out_proj_w
    cast_bf16<<<1024, 256, 0, stream>>>(out_proj_w, owbf);

    // K3: x_dbl split-K MFMA + reduce
    gemm_xproj<<<dim3(M / 128, SPLITK), 256, 0, stream>>>(
        (const short*)xtbf, (const short*)xpwbf, ppart);
    reduce_xdbl<<<XDBL_SZ / 256, 256, 0, stream>>>(ppart, xdbl);

    // K4: delta = softplus(x_dbl[:,:64] @ dt_proj_w^T + dt_proj_b)
    gemm_nt<2><<<dim3(DINNER / 64, M / 64), 256, 0, stream>>>(
        xdbl, 96, dt_proj_w, DTRANK, dlt, DINNER, dt_proj_b, DINNER, DTRANK);

    // K5-7: chunked scan
    scan_phaseA<<<dim3(DINNER / 256, NCHUNK, BSZ), 256, 0, stream>>>(
        xdbl, dlt, xtbf, A_log, Pbuf, Sbuf);
    scan_phaseB<<<NROW16 / 256, 256, 0, stream>>>(Pbuf, Sbuf, Hbuf);
    scan_phaseC<<<dim3(DINNER / 256, NCHUNK, BSZ), 256, 0, stream>>>(
        xdbl, dlt, xtbf, zbf, A_log, Dvec, Hbuf, ybf);

    // K8: out = y @ out_proj_w^T (bf16 MFMA)
    gemm_bf16<0><<<dim3(DMODEL / 128, M / 128), 256, 0, stream>>>(
        (const short*)ybf, (const short*)owbf, out, DMODEL, nullptr, DINNER);
}

// Round 6
// 343.646 us; speedup vs baseline: 1.1709x; 1.1709x over previous
//
#include <hip/hip_runtime.h>
#include <math.h>

// ---------------------------------------------------------------------------
// Mamba forward. All GEMMs bf16 MFMA; conv + scan fp32 compute, bf16 storage.
//   K0 cast_all: hidden/in_proj_w/out_proj_w/dt_proj_w/x_proj_w(pad128) -> bf16
//   K1 gemm_bf16<1>: xz = hbf @ wbf^T -> xbf bf16, zbf bf16
//   K2 conv_silu: causal conv4 + bias + SiLU (bf16 in) -> xtbf bf16
//   K3 gemm_xproj (split-K=16 MFMA) + reduce_xdbl -> xdbl fp32 + dtlo bf16
//   K4 gemm_bf16<2>: delta = softplus(dtlo @ dtw^T + b) -> dlt fp32 (MFMA K=64)
//   K5-7 chunked scan (64 chunks x 32 steps), B/C via LDS broadcast
//   K8 gemm_n64: out = ybf @ owbf^T (128x64 tile, 512 blocks)
// Round-6 fix: cast_all hidden range was 4096 blocks (2x OOB -> device
// fault + hbf overflow into wbf). Correct: 2048 blocks, total grid 5312.
// ---------------------------------------------------------------------------

#define DMODEL 1024
#define DINNER 2048
#define DSTATE 16
#define DTRANK 64
#define BSZ    2
#define LSEQ   2048
#define NCHUNK 64
#define CLEN   32
#define SPLITK 16
#define KCH    (DINNER / SPLITK)   // 128
#define XDBL_N 96
#define XDBL_SZ (BSZ*LSEQ*XDBL_N)  // 393216
#define NROW16 (BSZ*DINNER*DSTATE) // 65536 state rows

typedef __attribute__((ext_vector_type(8))) short bf16x8;
typedef __attribute__((ext_vector_type(8))) unsigned short u16x8;
typedef __attribute__((ext_vector_type(4))) unsigned short u16x4;
typedef __attribute__((ext_vector_type(4))) float f32x4;

__device__ __forceinline__ float silu_f(float v) {
    return v / (1.f + __expf(-v));
}
__device__ __forceinline__ float softplus_f(float v) {
    return (v > 20.f) ? v : log1pf(expf(v));
}
__device__ __forceinline__ unsigned short f2bf(float f) {
    unsigned int u = __float_as_uint(f);
    unsigned int r = (u + 0x7fffu + ((u >> 16) & 1u)) >> 16;   // RNE
    return (unsigned short)r;
}
__device__ __forceinline__ float bf2f(unsigned short u) {
    return __uint_as_float(((unsigned int)u) << 16);
}
__device__ __forceinline__ void gl_lds16(const void* g, void* l) {
    __builtin_amdgcn_global_load_lds(
        (const __attribute__((address_space(1))) unsigned int*)g,
        (__attribute__((address_space(3))) unsigned int*)l, 16, 0, 0);
}
__device__ __forceinline__ void cast8(const float* __restrict__ src,
                                      unsigned short* __restrict__ dst, size_t i) {
    float4 a = ((const float4*)src)[2 * i];
    float4 b = ((const float4*)src)[2 * i + 1];
    u16x8 v;
    v[0] = f2bf(a.x); v[1] = f2bf(a.y); v[2] = f2bf(a.z); v[3] = f2bf(a.w);
    v[4] = f2bf(b.x); v[5] = f2bf(b.y); v[6] = f2bf(b.z); v[7] = f2bf(b.w);
    *(u16x8*)(dst + 8 * i) = v;
}

// ---------------------------------------------------------------------------
// K0: all weight/input casts in one launch. Block ranges (8 elems/thread):
//  [0,2048)      hidden      4M elems
//  [2048,4096)   in_proj_w   4M
//  [4096,5120)   out_proj_w  2M
//  [5120,5184)   dt_proj_w   128K
//  [5184,5312)   x_proj_w -> 128-row padded dst (256K over dst)
// ---------------------------------------------------------------------------
__global__ __launch_bounds__(256) void cast_all(
    const float* __restrict__ hidden, const float* __restrict__ ipw,
    const float* __restrict__ opw, const float* __restrict__ dtw,
    const float* __restrict__ xpw,
    unsigned short* __restrict__ hbf, unsigned short* __restrict__ wbf,
    unsigned short* __restrict__ owbf, unsigned short* __restrict__ dtwbf,
    unsigned short* __restrict__ xpwbf)
{
    int bid = blockIdx.x;
    if (bid < 2048) {
        cast8(hidden, hbf, (size_t)bid * 256 + threadIdx.x);
    } else if (bid < 4096) {
        cast8(ipw, wbf, (size_t)(bid - 2048) * 256 + threadIdx.x);
    } else if (bid < 5120) {
        cast8(opw, owbf, (size_t)(bid - 4096) * 256 + threadIdx.x);
    } else if (bid < 5184) {
        cast8(dtw, dtwbf, (size_t)(bid - 5120) * 256 + threadIdx.x);
    } else {
        size_t i = (size_t)(bid - 5184) * 256 + threadIdx.x;
        size_t o = i * 8;
        int row = (int)(o >> 11);
        u16x8 v = {0, 0, 0, 0, 0, 0, 0, 0};
        if (row < 96) {
            float4 a = ((const float4*)xpw)[2 * i];
            float4 b = ((const float4*)xpw)[2 * i + 1];
            v[0] = f2bf(a.x); v[1] = f2bf(a.y); v[2] = f2bf(a.z); v[3] = f2bf(a.w);
            v[4] = f2bf(b.x); v[5] = f2bf(b.y); v[6] = f2bf(b.z); v[7] = f2bf(b.w);
        }
        *(u16x8*)(xpwbf + o) = v;
    }
}

// ---------------------------------------------------------------------------
// bf16 MFMA GEMM (NT): C[m,n] = sum_k A[m,k]*B[n,k]
// 128x128 tile, BK=32, 256 thr (4 waves), global_load_lds width-16 staging.
// EPI 0: C fp32 [m*ldc+n]
// EPI 1: n<DINNER -> xb bf16 ; else zb bf16   (both [m*DINNER + .])
// EPI 2: C fp32 = softplus(acc + bias[n])
// ---------------------------------------------------------------------------
template<int EPI>
__global__ __launch_bounds__(256) void gemm_bf16(
    const short* __restrict__ A, const short* __restrict__ B,
    float* __restrict__ C, int ldc,
    unsigned short* __restrict__ xb, unsigned short* __restrict__ zb,
    const float* __restrict__ bias, int K)
{
    __shared__ __align__(16) short As[128 * 32];
    __shared__ __align__(16) short Bs[128 * 32];
    const int t = threadIdx.x;
    const int wave = t >> 6, lane = t & 63;
    const int m0 = blockIdx.y * 128, n0 = blockIdx.x * 128;
    const int wm = (wave & 1) * 64, wn = (wave >> 1) * 64;
    const int srow = t >> 2;
    const int sq = (t & 3) * 16;

    const short* Ag = A + (size_t)(m0 + srow) * K;
    const short* Bg = B + (size_t)(n0 + srow) * K;
    char* AsL0 = (char*)As + wave * 1024;
    char* AsL1 = (char*)As + 4096 + wave * 1024;
    char* BsL0 = (char*)Bs + wave * 1024;
    char* BsL1 = (char*)Bs + 4096 + wave * 1024;

    const int quad = lane >> 4, l16 = lane & 15;
    const int aoff = (wm + l16) * 32 + quad * 8;
    const int boff = (wn + l16) * 32 + quad * 8;

    f32x4 acc[4][4];
#pragma unroll
    for (int i = 0; i < 4; i++)
#pragma unroll
        for (int j = 0; j < 4; j++) {
            f32x4 z = {0.f, 0.f, 0.f, 0.f};
            acc[i][j] = z;
        }

    for (int k0 = 0; k0 < K; k0 += 32) {
        __syncthreads();
        gl_lds16((const char*)(Ag + k0) + sq, AsL0);
        gl_lds16((const char*)(Ag + (size_t)64 * K + k0) + sq, AsL1);
        gl_lds16((const char*)(Bg + k0) + sq, BsL0);
        gl_lds16((const char*)(Bg + (size_t)64 * K + k0) + sq, BsL1);
        __syncthreads();
        bf16x8 af[4], bfr[4];
#pragma unroll
        for (int i = 0; i < 4; i++) {
            af[i]  = *(const bf16x8*)(As + aoff + i * 16 * 32);
            bfr[i] = *(const bf16x8*)(Bs + boff + i * 16 * 32);
        }
#pragma unroll
        for (int i = 0; i < 4; i++)
#pragma unroll
            for (int j = 0; j < 4; j++)
                acc[i][j] = __builtin_amdgcn_mfma_f32_16x16x32_bf16(
                    af[i], bfr[j], acc[i][j], 0, 0, 0);
    }

    // C/D layout: col(n) = lane&15, row(m) = quad*4 + reg
#pragma unroll
    for (int i = 0; i < 4; i++) {
        int mrow = m0 + wm + i * 16 + quad * 4;
#pragma unroll
        for (int j = 0; j < 4; j++) {
            int n = n0 + wn + j * 16 + l16;
            if (EPI == 1) {
                unsigned short* dst = (n0 < DINNER) ? xb : zb;
                int nn = (n0 < DINNER) ? n : (n - DINNER);
#pragma unroll
                for (int r = 0; r < 4; r++)
                    dst[(size_t)(mrow + r) * DINNER + nn] = f2bf(acc[i][j][r]);
            } else if (EPI == 2) {
                float bv = bias[n];
#pragma unroll
                for (int r = 0; r < 4; r++)
                    C[(size_t)(mrow + r) * ldc + n] =
                        softplus_f(acc[i][j][r] + bv);
            } else {
#pragma unroll
                for (int r = 0; r < 4; r++)
                    C[(size_t)(mrow + r) * ldc + n] = acc[i][j][r];
            }
        }
    }
}

// ---------------------------------------------------------------------------
// K8: 128M x 64N tile, BK=32, 4 waves (each 32M x 64N). 512 blocks.
// ---------------------------------------------------------------------------
__global__ __launch_bounds__(256) void gemm_n64(
    const short* __restrict__ A, const short* __restrict__ B,
    float* __restrict__ C, int ldc, int K)
{
    __shared__ __align__(16) short As[128 * 32];
    __shared__ __align__(16) short Bs[64 * 32];
    const int t = threadIdx.x;
    const int wave = t >> 6, lane = t & 63;
    const int m0 = blockIdx.y * 128, n0 = blockIdx.x * 64;
    const int wm = wave * 32;
    const int srow = t >> 2;
    const int sq = (t & 3) * 16;

    const short* Ag = A + (size_t)(m0 + srow) * K;
    const short* Bg = B + (size_t)(n0 + srow) * K;
    char* AsL0 = (char*)As + wave * 1024;
    char* AsL1 = (char*)As + 4096 + wave * 1024;
    char* BsL0 = (char*)Bs + wave * 1024;

    const int quad = lane >> 4, l16 = lane & 15;

    f32x4 acc[2][4];
#pragma unroll
    for (int i = 0; i < 2; i++)
#pragma unroll
        for (int j = 0; j < 4; j++) {
            f32x4 z = {0.f, 0.f, 0.f, 0.f};
            acc[i][j] = z;
        }

    for (int k0 = 0; k0 < K; k0 += 32) {
        __syncthreads();
        gl_lds16((const char*)(Ag + k0) + sq, AsL0);
        gl_lds16((const char*)(Ag + (size_t)64 * K + k0) + sq, AsL1);
        gl_lds16((const char*)(Bg + k0) + sq, BsL0);
        __syncthreads();
        bf16x8 af[2], bfr[4];
#pragma unroll
        for (int i = 0; i < 2; i++)
            af[i] = *(const bf16x8*)(As + (wm + i * 16 + l16) * 32 + quad * 8);
#pragma unroll
        for (int j = 0; j < 4; j++)
            bfr[j] = *(const bf16x8*)(Bs + (j * 16 + l16) * 32 + quad * 8);
#pragma unroll
        for (int i = 0; i < 2; i++)
#pragma unroll
            for (int j = 0; j < 4; j++)
                acc[i][j] = __builtin_amdgcn_mfma_f32_16x16x32_bf16(
                    af[i], bfr[j], acc[i][j], 0, 0, 0);
    }

#pragma unroll
    for (int i = 0; i < 2; i++) {
        int mrow = m0 + wm + i * 16 + quad * 4;
#pragma unroll
        for (int j = 0; j < 4; j++) {
            int n = n0 + j * 16 + l16;
#pragma unroll
            for (int r = 0; r < 4; r++)
                C[(size_t)(mrow + r) * ldc + n] = acc[i][j][r];
        }
    }
}

// ---------------------------------------------------------------------------
// K3: x_dbl split-K MFMA. grid (32, SPLITK). Partials -> ppart[kc][4096][96].
// ---------------------------------------------------------------------------
__global__ __launch_bounds__(256) void gemm_xproj(
    const short* __restrict__ Abf, const short* __restrict__ Bbf,
    float* __restrict__ ppart)
{
    __shared__ __align__(16) short As[128 * 32];
    __shared__ __align__(16) short Bs[128 * 32];
    const int t = threadIdx.x;
    const int wave = t >> 6, lane = t & 63;
    const int m0 = blockIdx.x * 128;
    const int kc = blockIdx.y;
    const int srow = t >> 2;
    const int sq = (t & 3) * 16;

    const short* Ag = Abf + (size_t)(m0 + srow) * DINNER;
    const short* Bg = Bbf + (size_t)srow * DINNER;
    char* AsL0 = (char*)As + wave * 1024;
    char* AsL1 = (char*)As + 4096 + wave * 1024;
    char* BsL0 = (char*)Bs + wave * 1024;
    char* BsL1 = (char*)Bs + 4096 + wave * 1024;

    const int quad = lane >> 4, l16 = lane & 15;
    const int wm = wave * 32;

    f32x4 acc[2][6];
#pragma unroll
    for (int i = 0; i < 2; i++)
#pragma unroll
        for (int j = 0; j < 6; j++) {
            f32x4 z = {0.f, 0.f, 0.f, 0.f};
            acc[i][j] = z;
        }

    for (int k0 = kc * KCH; k0 < kc * KCH + KCH; k0 += 32) {
        __syncthreads();
        gl_lds16((const char*)(Ag + k0) + sq, AsL0);
        gl_lds16((const char*)(Ag + (size_t)64 * DINNER + k0) + sq, AsL1);
        gl_lds16((const char*)(Bg + k0) + sq, BsL0);
        gl_lds16((const char*)(Bg + (size_t)64 * DINNER + k0) + sq, BsL1);
        __syncthreads();
        bf16x8 af[2], bfr[6];
#pragma unroll
        for (int i = 0; i < 2; i++)
            af[i] = *(const bf16x8*)(As + (wm + i * 16 + l16) * 32 + quad * 8);
#pragma unroll
        for (int j = 0; j < 6; j++)
            bfr[j] = *(const bf16x8*)(Bs + (j * 16 + l16) * 32 + quad * 8);
#pragma unroll
        for (int i = 0; i < 2; i++)
#pragma unroll
            for (int j = 0; j < 6; j++)
                acc[i][j] = __builtin_amdgcn_mfma_f32_16x16x32_bf16(
                    af[i], bfr[j], acc[i][j], 0, 0, 0);
    }

    float* dst = ppart + (size_t)kc * XDBL_SZ;
#pragma unroll
    for (int i = 0; i < 2; i++) {
        int mrow = m0 + wm + i * 16 + quad * 4;
#pragma unroll
        for (int j = 0; j < 6; j++) {
            int n = j * 16 + l16;
#pragma unroll
            for (int r = 0; r < 4; r++)
                dst[(size_t)(mrow + r) * XDBL_N + n] = acc[i][j][r];
        }
    }
}

// also emits dt_lo (cols 0..63) as bf16 for the K4 MFMA
__global__ __launch_bounds__(256) void reduce_xdbl(
    const float* __restrict__ ppart, float* __restrict__ xdbl,
    unsigned short* __restrict__ dtlobf)
{
    int i = blockIdx.x * 256 + threadIdx.x;
    float s = 0.f;
#pragma unroll
    for (int c = 0; c < SPLITK; c++) s += ppart[(size_t)c * XDBL_SZ + i];
    xdbl[i] = s;
    int m = i / XDBL_N;
    int n = i - m * XDBL_N;
    if (n < DTRANK) dtlobf[(size_t)m * DTRANK + n] = f2bf(s);
}

// ---------------------------------------------------------------------------
// Causal conv4 + bias + SiLU, (b,l,ch) bf16 in, bf16 out. 4 ch per thread.
// ---------------------------------------------------------------------------
__global__ __launch_bounds__(256) void conv_silu(
    const unsigned short* __restrict__ xb, const float* __restrict__ convw,
    const float* __restrict__ convb, unsigned short* __restrict__ xtbf)
{
    int i = blockIdx.x * 256 + threadIdx.x;
    int c4 = i & 511;
    int m  = i >> 9;
    int l  = m & (LSEQ - 1);
    int ch = c4 * 4;
    const u16x4* base = (const u16x4*)xb + (size_t)m * 512 + c4;
    u16x4 vz = {0, 0, 0, 0};
    u16x4 v3 = base[0];
    u16x4 v2 = (l >= 1) ? base[-512]  : vz;
    u16x4 v1 = (l >= 2) ? base[-1024] : vz;
    u16x4 v0 = (l >= 3) ? base[-1536] : vz;
    float4 t0 = ((const float4*)convw)[ch + 0];
    float4 t1 = ((const float4*)convw)[ch + 1];
    float4 t2 = ((const float4*)convw)[ch + 2];
    float4 t3 = ((const float4*)convw)[ch + 3];
    float4 bv = ((const float4*)convb)[c4];
    u16x4 o;
    o[0] = f2bf(silu_f(bv.x + t0.x * bf2f(v0[0]) + t0.y * bf2f(v1[0]) +
                       t0.z * bf2f(v2[0]) + t0.w * bf2f(v3[0])));
    o[1] = f2bf(silu_f(bv.y + t1.x * bf2f(v0[1]) + t1.y * bf2f(v1[1]) +
                       t1.z * bf2f(v2[1]) + t1.w * bf2f(v3[1])));
    o[2] = f2bf(silu_f(bv.z + t2.x * bf2f(v0[2]) + t2.y * bf2f(v1[2]) +
                       t2.z * bf2f(v2[2]) + t2.w * bf2f(v3[2])));
    o[3] = f2bf(silu_f(bv.w + t3.x * bf2f(v0[3]) + t3.y * bf2f(v1[3]) +
                       t3.z * bf2f(v2[3]) + t3.w * bf2f(v3[3])));
    *(u16x4*)(xtbf + (size_t)m * DINNER + ch) = o;
}

// ---------------------------------------------------------------------------
// Chunked selective scan: thread = one (b,d,chunk), 16 states in registers.
// grid (DINNER/256, NCHUNK, BSZ) = 1024 blocks. B/C staged in LDS; per-step
// LDS reads are wave-uniform broadcast. Manual one-step load-ahead.
// ---------------------------------------------------------------------------
__global__ __launch_bounds__(256) void scan_phaseA(
    const float* __restrict__ xdbl, const float* __restrict__ dlt,
    const unsigned short* __restrict__ xtbf, const float* __restrict__ A_log,
    float* __restrict__ Pbuf, float* __restrict__ Sbuf)
{
    __shared__ float Bsh[CLEN][16];
    const int d = blockIdx.x * 256 + threadIdx.x;
    const int c = blockIdx.y, b = blockIdx.z;
    if (threadIdx.x < CLEN * 4) {
        int lr = threadIdx.x >> 2, p = threadIdx.x & 3;
        const float* src = xdbl +
            ((size_t)b * LSEQ + (size_t)c * CLEN + lr) * XDBL_N + DTRANK + p * 4;
        *(float4*)&Bsh[lr][p * 4] = *(const float4*)src;
    }
    __syncthreads();

    float A[16], P[16], S[16];
#pragma unroll
    for (int q = 0; q < 4; q++) {
        float4 a4 = *(const float4*)(A_log + d * DSTATE + q * 4);
        A[4 * q] = -__expf(a4.x); A[4 * q + 1] = -__expf(a4.y);
        A[4 * q + 2] = -__expf(a4.z); A[4 * q + 3] = -__expf(a4.w);
    }
#pragma unroll
    for (int j = 0; j < 16; j++) { P[j] = 1.f; S[j] = 0.f; }

    size_t off = ((size_t)b * LSEQ + (size_t)c * CLEN) * DINNER + d;
    float dvn = dlt[off];
    float xvn = bf2f(xtbf[off]);
    for (int ll = 0; ll < CLEN; ++ll) {
        float dv = dvn, xv = xvn;
        if (ll + 1 < CLEN) {
            off += DINNER;
            dvn = dlt[off];
            xvn = bf2f(xtbf[off]);
        }
        float dx = dv * xv;
        f32x4 Bq[4];
#pragma unroll
        for (int q = 0; q < 4; q++) Bq[q] = *(const f32x4*)&Bsh[ll][q * 4];
#pragma unroll
        for (int j = 0; j < 16; j++) {
            float dA = __expf(dv * A[j]);
            P[j] *= dA;
            S[j] = fmaf(dA, S[j], dx * Bq[j >> 2][j & 3]);
        }
    }
    size_t o = ((size_t)c * BSZ * DINNER + (size_t)b * DINNER + d) * 16;
#pragma unroll
    for (int q = 0; q < 4; q++) {
        *(float4*)(Pbuf + o + q * 4) =
            make_float4(P[4 * q], P[4 * q + 1], P[4 * q + 2], P[4 * q + 3]);
        *(float4*)(Sbuf + o + q * 4) =
            make_float4(S[4 * q], S[4 * q + 1], S[4 * q + 2], S[4 * q + 3]);
    }
}

__global__ __launch_bounds__(256) void scan_phaseB(
    const float* __restrict__ Pbuf, const float* __restrict__ Sbuf,
    float* __restrict__ Hbuf)
{
    int r = blockIdx.x * 256 + threadIdx.x;   // 65536 state rows
    float run = 0.f;
    for (int c = 0; c < NCHUNK; ++c) {
        size_t o = (size_t)c * NROW16 + r;
        Hbuf[o] = run;
        run = Pbuf[o] * run + Sbuf[o];
    }
}

__global__ __launch_bounds__(256) void scan_phaseC(
    const float* __restrict__ xdbl, const float* __restrict__ dlt,
    const unsigned short* __restrict__ xtbf, const unsigned short* __restrict__ zbf,
    const float* __restrict__ A_log, const float* __restrict__ Dvec,
    const float* __restrict__ Hbuf, unsigned short* __restrict__ ybf)
{
    __shared__ float BCsh[CLEN][32];   // [l][0:16]=B, [l][16:32]=C
    const int d = blockIdx.x * 256 + threadIdx.x;
    const int c = blockIdx.y, b = blockIdx.z;
    {
        int lr = threadIdx.x >> 3, p = threadIdx.x & 7;
        const float* src = xdbl +
            ((size_t)b * LSEQ + (size_t)c * CLEN + lr) * XDBL_N + DTRANK;
        *(float4*)&BCsh[lr][p * 4] = *(const float4*)(src + p * 4);
    }
    __syncthreads();

    float A[16], h[16];
#pragma unroll
    for (int q = 0; q < 4; q++) {
        float4 a4 = *(const float4*)(A_log + d * DSTATE + q * 4);
        A[4 * q] = -__expf(a4.x); A[4 * q + 1] = -__expf(a4.y);
        A[4 * q + 2] = -__expf(a4.z); A[4 * q + 3] = -__expf(a4.w);
    }
    size_t o = ((size_t)c * BSZ * DINNER + (size_t)b * DINNER + d) * 16;
#pragma unroll
    for (int q = 0; q < 4; q++) {
        float4 h4 = *(const float4*)(Hbuf + o + q * 4);
        h[4 * q] = h4.x; h[4 * q + 1] = h4.y;
        h[4 * q + 2] = h4.z; h[4 * q + 3] = h4.w;
    }
    float Dd = Dvec[d];
    size_t off = ((size_t)b * LSEQ + (size_t)c * CLEN) * DINNER + d;
    float dvn = dlt[off];
    float xvn = bf2f(xtbf[off]);
    float zvn = bf2f(zbf[off]);
    size_t offc = off;
    for (int ll = 0; ll < CLEN; ++ll) {
        float dv = dvn, xv = xvn, zv = zvn;
        size_t offw = offc;
        if (ll + 1 < CLEN) {
            offc += DINNER;
            dvn = dlt[offc];
            xvn = bf2f(xtbf[offc]);
            zvn = bf2f(zbf[offc]);
        }
        float dx = dv * xv;
        f32x4 Bq[4], Cq[4];
#pragma unroll
        for (int q = 0; q < 4; q++) {
            Bq[q] = *(const f32x4*)&BCsh[ll][q * 4];
            Cq[q] = *(const f32x4*)&BCsh[ll][16 + q * 4];
        }
        float yp = 0.f;
#pragma unroll
        for (int j = 0; j < 16; j++) {
            float dA = __expf(dv * A[j]);
            h[j] = fmaf(dA, h[j], dx * Bq[j >> 2][j & 3]);
            yp = fmaf(h[j], Cq[j >> 2][j & 3], yp);
        }
        float yv = yp + Dd * xv;
        yv *= zv / (1.f + __expf(-zv));
        ybf[offw] = f2bf(yv);
    }
}

// ---------------------------------------------------------------------------
extern "C" void kernel_launch(void* const* d_in, const int* in_sizes, int n_in,
                              void* d_out, int out_size, void* d_ws, size_t ws_size,
                              hipStream_t stream)
{
    const float* hidden     = (const float*)d_in[0];
    const float* in_proj_w  = (const float*)d_in[1];
    const float* conv_w     = (const float*)d_in[2];
    const float* conv_b     = (const float*)d_in[3];
    const float* x_proj_w   = (const float*)d_in[4];
    const float* dt_proj_w  = (const float*)d_in[5];
    const float* dt_proj_b  = (const float*)d_in[6];
    const float* A_log      = (const float*)d_in[7];
    const float* Dvec       = (const float*)d_in[8];
    const float* out_proj_w = (const float*)d_in[9];
    float* out = (float*)d_out;

    // workspace (float units), 35 MF = 140 MB:
    //  [0,4)      xbf (bf16, K1->K2)  / dlt [0,8) fp32 (K4->scan)  [disjoint]
    //  [8,12)     zbf  (bf16)
    //  [12,16)    xtbf (bf16)
    //  [16,20)    Pbuf ; [20,24) Sbuf ; [24,28) Hbuf
    //             ppart aliases [16,22) (K3->reduce, before scan)
    //  [28,28.125)  xpwbf ; [28.25,28.625) xdbl fp32
    //  [29,30)    owbf ; [30,30.0625) dtwbf ; [30.25,30.375) dtlobf
    //  [31,33)    hbf ; [33,35) wbf ; ybf aliases [31,35)
    const size_t MF = 1024 * 1024;
    float* ws = (float*)d_ws;
    unsigned short* xbf  = (unsigned short*)ws;
    float* dlt   = ws;
    unsigned short* zbf  = (unsigned short*)(ws + 8 * MF);
    unsigned short* xtbf = (unsigned short*)(ws + 12 * MF);
    float* Pbuf  = ws + 16 * MF;
    float* Sbuf  = ws + 20 * MF;
    float* Hbuf  = ws + 24 * MF;
    float* ppart = ws + 16 * MF;
    unsigned short* xpwbf  = (unsigned short*)(ws + 28 * MF);
    float* xdbl  = ws + 28 * MF + MF / 4;
    unsigned short* owbf   = (unsigned short*)(ws + 29 * MF);
    unsigned short* dtwbf  = (unsigned short*)(ws + 30 * MF);
    unsigned short* dtlobf = (unsigned short*)(ws + 30 * MF + MF / 4);
    unsigned short* hbf    = (unsigned short*)(ws + 31 * MF);
    unsigned short* wbf    = (unsigned short*)(ws + 33 * MF);
    unsigned short* ybf    = hbf;   // reused after K1

    const int M = BSZ * LSEQ;   // 4096

    // K0: all casts
    cast_all<<<5312, 256, 0, stream>>>(hidden, in_proj_w, out_proj_w,
                                       dt_proj_w, x_proj_w,
                                       hbf, wbf, owbf, dtwbf, xpwbf);

    // K1: xz = hidden @ in_proj_w^T (bf16 MFMA) -> xbf, zbf (both bf16)
    gemm_bf16<1><<<dim3(2 * DINNER / 128, M / 128), 256, 0, stream>>>(
        (const short*)hbf, (const short*)wbf, nullptr, 0, xbf, zbf,
        nullptr, DMODEL);

    // K2: conv + SiLU (bf16 -> bf16)
    conv_silu<<<(M * 512) / 256, 256, 0, stream>>>(xbf, conv_w, conv_b, xtbf);

    // K3: x_dbl split-K MFMA + reduce (emits fp32 xdbl + bf16 dt_lo)
    gemm_xproj<<<dim3(M / 128, SPLITK), 256, 0, stream>>>(
        (const short*)xtbf, (const short*)xpwbf, ppart);
    reduce_xdbl<<<XDBL_SZ / 256, 256, 0, stream>>>(ppart, xdbl, dtlobf);

    // K4: delta = softplus(dt_lo @ dt_proj_w^T + dt_proj_b)  (MFMA, K=64)
    gemm_bf16<2><<<dim3(DINNER / 128, M / 128), 256, 0, stream>>>(
        (const short*)dtlobf, (const short*)dtwbf, dlt, DINNER,
        nullptr, nullptr, dt_proj_b, DTRANK);

    // K5-7: chunked scan (64 chunks x 32 steps)
    scan_phaseA<<<dim3(DINNER / 256, NCHUNK, BSZ), 256, 0, stream>>>(
        xdbl, dlt, xtbf, A_log, Pbuf, Sbuf);
    scan_phaseB<<<NROW16 / 256, 256, 0, stream>>>(Pbuf, Sbuf, Hbuf);
    scan_phaseC<<<dim3(DINNER / 256, NCHUNK, BSZ), 256, 0, stream>>>(
        xdbl, dlt, xtbf, zbf, A_log, Dvec, Hbuf, ybf);

    // K8: out = y @ out_proj_w^T (128x64 tile, 512 blocks)
    gemm_n64<<<dim3(DMODEL / 64, M / 128), 256, 0, stream>>>(
        (const short*)ybf, (const short*)owbf, out, DMODEL, DINNER);
}